// Round 11
// baseline (105.216 us; speedup 1.0000x reference)
//
#include <hip/hip_runtime.h>
#include <stdint.h>

typedef __attribute__((ext_vector_type(8))) short bf16x8;
typedef __attribute__((ext_vector_type(8))) unsigned short u16x8;
typedef __attribute__((ext_vector_type(4))) float f32x4;
typedef unsigned short u16;

constexpr int NN = 2048, NF = 256;

__device__ inline u16 f2bf(float f) {
  uint32_t u = __builtin_bit_cast(uint32_t, f);
  uint32_t r = (u + 0x7FFFu + ((u >> 16) & 1u)) >> 16;
  return (u16)r;
}
__device__ inline float bf2f(u16 h) {
  uint32_t u = ((uint32_t)h) << 16;
  return __builtin_bit_cast(float, u);
}

// ---- K1: d[row]=rsqrt(1+sum adj[row,:]); tail blocks: Wconv ----------------
__global__ __launch_bounds__(256) void k_rowsum(const float* __restrict__ adj,
                                                float* __restrict__ d,
                                                const float* __restrict__ W,
                                                u16* __restrict__ Wb) {
  if (blockIdx.x >= 16384) {  // W fp32 -> bf16 (64 blocks)
    int i = (blockIdx.x - 16384) * 256 + threadIdx.x;
    float4 v = ((const float4*)W)[i];
    ushort4 o;
    o.x = f2bf(v.x); o.y = f2bf(v.y); o.z = f2bf(v.z); o.w = f2bf(v.w);
    *(ushort4*)(Wb + (size_t)i * 4) = o;
    return;
  }
  int row = blockIdx.x;
  const float4* p = (const float4*)(adj + (size_t)row * NN);
  float s = 0.f;
#pragma unroll
  for (int c = 0; c < 2; ++c) {
    float4 v = p[threadIdx.x + 256 * c];
    s += v.x + v.y + v.z + v.w;
  }
#pragma unroll
  for (int off = 32; off > 0; off >>= 1) s += __shfl_down(s, off, 64);
  __shared__ float red[4];
  int lane = threadIdx.x & 63, w = threadIdx.x >> 6;
  if (lane == 0) red[w] = s;
  __syncthreads();
  if (threadIdx.x == 0) {
    float t = red[0] + red[1] + red[2] + red[3] + 1.0f;
    d[row] = 1.0f / sqrtf(t);
  }
}

// ---- K2: XpT[b,f,j] = bf16(d_j * X[b,j,f])  (plain transpose) --------------
__global__ __launch_bounds__(256) void k_xprep(const float* __restrict__ X,
                                               const float* __restrict__ d,
                                               u16* __restrict__ XpT) {
  int jt = blockIdx.x, ft = blockIdx.y, b = blockIdx.z;
  int j0 = jt * 64, f0 = ft * 64;
  __shared__ u16 T[64][66];
  int t = threadIdx.x;
#pragma unroll
  for (int s = 0; s < 4; ++s) {
    int q = s * 256 + t;
    int r = q >> 4, c4 = q & 15;
    int j = j0 + r;
    float dv = d[b * NN + j];
    float4 v = *(const float4*)(X + ((size_t)(b * NN + j)) * NF + f0 + c4 * 4);
    T[r][c4 * 4 + 0] = f2bf(v.x * dv);
    T[r][c4 * 4 + 1] = f2bf(v.y * dv);
    T[r][c4 * 4 + 2] = f2bf(v.z * dv);
    T[r][c4 * 4 + 3] = f2bf(v.w * dv);
  }
  __syncthreads();
#pragma unroll
  for (int s = 0; s < 4; ++s) {
    int q = s * 256 + t;
    int fr = q >> 4, c4 = q & 15;
    ushort4 o;
    o.x = T[c4 * 4 + 0][fr]; o.y = T[c4 * 4 + 1][fr];
    o.z = T[c4 * 4 + 2][fr]; o.w = T[c4 * 4 + 3][fr];
    *(ushort4*)(XpT + ((size_t)(b * NF + f0 + fr)) * NN + j0 + c4 * 4) = o;
  }
}

// ---- Fused: H = d_i*(adj@Xp + Xp_i) ; out = relu(H@W^T + bias) -------------
// BM=64, BN=256, BK=32, 512 thr (8 waves 2x4), grid 256 = 1 block/CU.
// B: registers only — depth-3 sets (bsA/bsB/bsC) loaded direct from L2,
//    compiler-managed waits (no manual vmcnt anywhere).
// A: fp32 adj (L3) -> regs (3 sets mod-3) -> cvt -> ds_write; granules mod-3;
//    ONE s_barrier per pair (2 K-steps).
#define BLOAD(SET, K)                                                          \
    SET[0] = *(const bf16x8*)(bp0 + (size_t)(K) * 32);                         \
    SET[1] = *(const bf16x8*)(bp1 + (size_t)(K) * 32);                         \
    SET[2] = *(const bf16x8*)(bp2 + (size_t)(K) * 32);                         \
    SET[3] = *(const bf16x8*)(bp3 + (size_t)(K) * 32);

#define MFMA8(A0, A1, BS)                                                      \
    __builtin_amdgcn_s_setprio(1);                                             \
    acc[0][0] = __builtin_amdgcn_mfma_f32_16x16x32_bf16(A0, BS[0], acc[0][0], 0, 0, 0); \
    acc[0][1] = __builtin_amdgcn_mfma_f32_16x16x32_bf16(A0, BS[1], acc[0][1], 0, 0, 0); \
    acc[0][2] = __builtin_amdgcn_mfma_f32_16x16x32_bf16(A0, BS[2], acc[0][2], 0, 0, 0); \
    acc[0][3] = __builtin_amdgcn_mfma_f32_16x16x32_bf16(A0, BS[3], acc[0][3], 0, 0, 0); \
    acc[1][0] = __builtin_amdgcn_mfma_f32_16x16x32_bf16(A1, BS[0], acc[1][0], 0, 0, 0); \
    acc[1][1] = __builtin_amdgcn_mfma_f32_16x16x32_bf16(A1, BS[1], acc[1][1], 0, 0, 0); \
    acc[1][2] = __builtin_amdgcn_mfma_f32_16x16x32_bf16(A1, BS[2], acc[1][2], 0, 0, 0); \
    acc[1][3] = __builtin_amdgcn_mfma_f32_16x16x32_bf16(A1, BS[3], acc[1][3], 0, 0, 0); \
    __builtin_amdgcn_s_setprio(0);

#define AWRITE(SW_, GW_)                                                       \
    {                                                                          \
      float4 c0 = aN0[SW_], c1 = aN1[SW_];                                     \
      u16x8 pk;                                                                \
      pk[0] = f2bf(c0.x); pk[1] = f2bf(c0.y); pk[2] = f2bf(c0.z);              \
      pk[3] = f2bf(c0.w); pk[4] = f2bf(c1.x); pk[5] = f2bf(c1.y);              \
      pk[6] = f2bf(c1.z); pk[7] = f2bf(c1.w);                                  \
      *(u16x8*)(smem + (GW_) * 8192 + a_ldst) = pk;                            \
    }

// One PAIR = K-steps 2G, 2G+1. GR: A granule read. GW/SW: granule/reg-set
// written (pair G+2 data). SL: reg set loaded (pair G+4). BS0/BS1: B sets.
#define PAIR(G, GR, GW, SL, SW, BS0n, BS1n, IA, WA, IB0, IB1)                  \
  {                                                                            \
    __builtin_amdgcn_s_barrier();                                              \
    __builtin_amdgcn_sched_barrier(0);                                         \
    bf16x8 a00 = *(const bf16x8*)(smem + (GR) * 8192 + aoff0);                 \
    bf16x8 a01 = *(const bf16x8*)(smem + (GR) * 8192 + aoff0 + 1024);          \
    bf16x8 a10 = *(const bf16x8*)(smem + (GR) * 8192 + 4096 + aoff0);          \
    bf16x8 a11 = *(const bf16x8*)(smem + (GR) * 8192 + 4096 + aoff0 + 1024);   \
    asm volatile("s_waitcnt lgkmcnt(2)" ::: "memory");                         \
    __builtin_amdgcn_sched_barrier(0);                                         \
    MFMA8(a00, a01, BS0n)                                                      \
    __builtin_amdgcn_sched_barrier(0);                                         \
    if (IB0) { BLOAD(BS0n, 2 * (G) + 3) }                                      \
    __builtin_amdgcn_sched_barrier(0);                                         \
    asm volatile("s_waitcnt lgkmcnt(0)" ::: "memory");                         \
    __builtin_amdgcn_sched_barrier(0);                                         \
    MFMA8(a10, a11, BS1n)                                                      \
    __builtin_amdgcn_sched_barrier(0);                                         \
    if (IB1) { BLOAD(BS1n, 2 * (G) + 4) }                                      \
    if (IA) {                                                                  \
      aN0[SL] = *(const float4*)(a_gsrc + (size_t)((G) + 4) * 64);             \
      aN1[SL] = *(const float4*)(a_gsrc + (size_t)((G) + 4) * 64 + 4);         \
    }                                                                          \
    if (WA) {                                                                  \
      AWRITE(SW, GW)                                                           \
      asm volatile("s_waitcnt lgkmcnt(0)" ::: "memory");                       \
    }                                                                          \
    __builtin_amdgcn_sched_barrier(0);                                         \
  }

__global__ __launch_bounds__(512, 2) void k_fused(
    const float* __restrict__ adj, const u16* __restrict__ XpT,
    const float* __restrict__ dsc, const u16* __restrict__ Wb,
    const float* __restrict__ bias, float* __restrict__ out) {
  int flat = blockIdx.x;
  int b = flat & 7, mt = flat >> 3;  // batch->XCD affinity
  int i0 = mt * 64;

  __shared__ __align__(16) char smem[36864];  // A 3x8K; Hs (33.8K) aliases
  u16* Hs = (u16*)smem;

  int t = threadIdx.x;
  int lane = t & 63, w = t >> 6;
  int l15 = lane & 15, l4 = lane >> 4;
  int wr = w >> 2, wc = w & 3;

  const float* adjf = adj + ((size_t)b * NN + i0) * NN;
  const u16* XpTb = XpT + (size_t)b * NF * NN;

  // A staging: thread t -> row rA=t>>3, 8-float chunk kc=t&7 per pair
  int rA = t >> 3, kc = t & 7;
  const float* a_gsrc = adjf + (size_t)rA * NN + kc * 8;
  int a_ldst = (kc >> 2) * 4096 + rA * 64 + (((kc & 3) ^ ((rA >> 1) & 3)) << 4);

  // A frag read offsets (granule-local)
  int swz = (l4 ^ ((l15 >> 1) & 3)) << 4;
  int aoff0 = wr * 2048 + l15 * 64 + swz;

  // B frag base pointers (registers path; plain XpT layout)
  const u16* bp0 = XpTb + (size_t)(wc * 64 + l15) * NN + l4 * 8;
  const u16* bp1 = bp0 + (size_t)16 * NN;
  const u16* bp2 = bp0 + (size_t)32 * NN;
  const u16* bp3 = bp0 + (size_t)48 * NN;

  f32x4 acc[2][4] = {};
  float4 aN0[3], aN1[3];
  bf16x8 bsA[4], bsB[4], bsC[4];

  // ---- prologue: B steps 0,1,2 -> sets; A pairs 0,1 -> granules 0,1;
  //      A pairs 2,3 -> reg sets 2,0 ----
  BLOAD(bsA, 0)
  BLOAD(bsB, 1)
  BLOAD(bsC, 2)
  {
    float4 p0a = *(const float4*)(a_gsrc);
    float4 p0b = *(const float4*)(a_gsrc + 4);
    float4 p1a = *(const float4*)(a_gsrc + 64);
    float4 p1b = *(const float4*)(a_gsrc + 68);
    aN0[2] = *(const float4*)(a_gsrc + 128);   // pair 2 -> set 2
    aN1[2] = *(const float4*)(a_gsrc + 132);
    aN0[0] = *(const float4*)(a_gsrc + 192);   // pair 3 -> set 0
    aN1[0] = *(const float4*)(a_gsrc + 196);
    u16x8 pk;
    pk[0] = f2bf(p0a.x); pk[1] = f2bf(p0a.y); pk[2] = f2bf(p0a.z);
    pk[3] = f2bf(p0a.w); pk[4] = f2bf(p0b.x); pk[5] = f2bf(p0b.y);
    pk[6] = f2bf(p0b.z); pk[7] = f2bf(p0b.w);
    *(u16x8*)(smem + a_ldst) = pk;             // granule 0
    pk[0] = f2bf(p1a.x); pk[1] = f2bf(p1a.y); pk[2] = f2bf(p1a.z);
    pk[3] = f2bf(p1a.w); pk[4] = f2bf(p1b.x); pk[5] = f2bf(p1b.y);
    pk[6] = f2bf(p1b.z); pk[7] = f2bf(p1b.w);
    *(u16x8*)(smem + 8192 + a_ldst) = pk;      // granule 1
    asm volatile("s_waitcnt lgkmcnt(0)" ::: "memory");
    __builtin_amdgcn_sched_barrier(0);
  }

  // ---- main loop: pairs 0..26 (period 3) ----
  for (int gb = 0; gb < 9; ++gb) {
    int g = gb * 3;
    PAIR(g + 0, 0, 2, 1, 2, bsA, bsB, 1, 1, 1, 1)
    PAIR(g + 1, 1, 0, 2, 0, bsC, bsA, 1, 1, 1, 1)
    PAIR(g + 2, 2, 1, 0, 1, bsB, bsC, 1, 1, 1, 1)
  }
  // ---- tail: pairs 27..31 ----
  PAIR(27, 0, 2, 1, 2, bsA, bsB, 1, 1, 1, 1)
  PAIR(28, 1, 0, 2, 0, bsC, bsA, 0, 1, 1, 1)
  PAIR(29, 2, 1, 0, 1, bsB, bsC, 0, 1, 1, 1)
  PAIR(30, 0, 0, 0, 0, bsA, bsB, 0, 0, 1, 0)
  PAIR(31, 1, 0, 0, 0, bsC, bsA, 0, 0, 0, 0)

  __syncthreads();  // drain everything before Hs aliases the A granules

  // ---- epilogue 1: H tile -> LDS bf16 [64][264]; +I term from XpT (L2) ----
  const float* db = dsc + b * NN;
#pragma unroll
  for (int mi = 0; mi < 2; ++mi) {
#pragma unroll
    for (int ni = 0; ni < 4; ++ni) {
      int f = wc * 64 + ni * 16 + l15;
      ushort4 xv = *(const ushort4*)(XpTb + (size_t)f * NN + i0 +
                                     wr * 32 + mi * 16 + l4 * 4);
#pragma unroll
      for (int qq = 0; qq < 4; ++qq) {
        int il = wr * 32 + mi * 16 + l4 * 4 + qq;
        float dv = db[i0 + il];
        float xpv = bf2f(((const u16*)&xv)[qq]);
        float hv = dv * (acc[mi][ni][qq] + xpv);
        Hs[il * 264 + f] = f2bf(hv);
      }
    }
  }
  __syncthreads();

  // ---- epilogue 2: out = relu(H @ W^T + bias), W frags from L2 ----
  f32x4 acc2[2][4] = {};
#pragma unroll
  for (int kk = 0; kk < 256; kk += 32) {
    bf16x8 a2[2], b2[4];
#pragma unroll
    for (int mi = 0; mi < 2; ++mi) {
      int r = wr * 32 + mi * 16 + l15;
      a2[mi] = *(const bf16x8*)&Hs[r * 264 + kk + l4 * 8];
    }
#pragma unroll
    for (int ni = 0; ni < 4; ++ni) {
      int o = wc * 64 + ni * 16 + l15;
      b2[ni] = *(const bf16x8*)&Wb[(size_t)o * 256 + kk + l4 * 8];
    }
#pragma unroll
    for (int mi = 0; mi < 2; ++mi)
#pragma unroll
      for (int ni = 0; ni < 4; ++ni)
        acc2[mi][ni] = __builtin_amdgcn_mfma_f32_16x16x32_bf16(a2[mi], b2[ni],
                                                               acc2[mi][ni], 0, 0, 0);
  }

  float* outb = out + ((size_t)b * NN + i0) * NF;
#pragma unroll
  for (int mi = 0; mi < 2; ++mi) {
#pragma unroll
    for (int qq = 0; qq < 4; ++qq) {
      int il = wr * 32 + mi * 16 + l4 * 4 + qq;
#pragma unroll
      for (int ni = 0; ni < 4; ++ni) {
        int o = wc * 64 + ni * 16 + l15;
        float v = acc2[mi][ni][qq] + bias[o];
        outb[(size_t)il * NF + o] = fmaxf(v, 0.f);
      }
    }
  }
}

extern "C" void kernel_launch(void* const* d_in, const int* in_sizes, int n_in,
                              void* d_out, int out_size, void* d_ws, size_t ws_size,
                              hipStream_t stream) {
  const float* X    = (const float*)d_in[0];
  const float* adj  = (const float*)d_in[1];
  const float* W    = (const float*)d_in[2];
  const float* bias = (const float*)d_in[3];
  float* out = (float*)d_out;

  char* ws = (char*)d_ws;
  float* dsc = (float*)(ws);                 // 64 KB
  u16*   Wb  = (u16*)(ws + 65536);           // 128 KB
  u16*   XpT = (u16*)(ws + 262144);          // 8 MB

  k_rowsum<<<dim3(16448), dim3(256), 0, stream>>>(adj, dsc, W, Wb);
  k_xprep<<<dim3(32, 4, 8), dim3(256), 0, stream>>>(X, dsc, XpT);
  k_fused<<<dim3(256), dim3(512), 0, stream>>>(adj, XpT, dsc, Wb, bias, out);
}

// Round 12
// 78.079 us; speedup vs baseline: 1.3476x; 1.3476x over previous
//
#include <hip/hip_runtime.h>
#include <stdint.h>

typedef __attribute__((ext_vector_type(8))) short bf16x8;
typedef __attribute__((ext_vector_type(8))) unsigned short u16x8;
typedef __attribute__((ext_vector_type(4))) float f32x4;
typedef unsigned short u16;

constexpr int NN = 2048, NF = 256;

__device__ inline u16 f2bf(float f) {
  uint32_t u = __builtin_bit_cast(uint32_t, f);
  uint32_t r = (u + 0x7FFFu + ((u >> 16) & 1u)) >> 16;
  return (u16)r;
}
__device__ inline float bf2f(u16 h) {
  uint32_t u = ((uint32_t)h) << 16;
  return __builtin_bit_cast(float, u);
}

__device__ inline void gload_lds16(const void* g, void* l) {
  __builtin_amdgcn_global_load_lds(
      (const __attribute__((address_space(1))) uint32_t*)g,
      (__attribute__((address_space(3))) uint32_t*)l,
      16, 0, 0);
}

// ---- K_pre: blocks [0,1024): YpT = bf16(X)^T (plain, no d);
//             [1024,1088): Wb = bf16(W); [1088,17472): rowsum -> d ----------
__global__ __launch_bounds__(256) void k_pre(const float* __restrict__ adj,
                                             float* __restrict__ d,
                                             const float* __restrict__ X,
                                             u16* __restrict__ YpT,
                                             const float* __restrict__ W,
                                             u16* __restrict__ Wb) {
  __shared__ u16 T[64][66];
  __shared__ float red[4];
  int bx = blockIdx.x, t = threadIdx.x;

  if (bx < 1024) {  // X transpose (no scaling)
    int jt = bx & 31, ft = (bx >> 5) & 3, b = bx >> 7;
    int j0 = jt * 64, f0 = ft * 64;
#pragma unroll
    for (int s = 0; s < 4; ++s) {
      int q = s * 256 + t;
      int r = q >> 4, c4 = q & 15;
      int j = j0 + r;
      float4 v = *(const float4*)(X + ((size_t)(b * NN + j)) * NF + f0 + c4 * 4);
      T[r][c4 * 4 + 0] = f2bf(v.x);
      T[r][c4 * 4 + 1] = f2bf(v.y);
      T[r][c4 * 4 + 2] = f2bf(v.z);
      T[r][c4 * 4 + 3] = f2bf(v.w);
    }
    __syncthreads();
#pragma unroll
    for (int s = 0; s < 4; ++s) {
      int q = s * 256 + t;
      int fr = q >> 4, c4 = q & 15;
      ushort4 o;
      o.x = T[c4 * 4 + 0][fr]; o.y = T[c4 * 4 + 1][fr];
      o.z = T[c4 * 4 + 2][fr]; o.w = T[c4 * 4 + 3][fr];
      *(ushort4*)(YpT + ((size_t)(b * NF + f0 + fr)) * NN + j0 + c4 * 4) = o;
    }
    return;
  }
  if (bx < 1088) {  // W conv
    int i = (bx - 1024) * 256 + t;
    float4 v = ((const float4*)W)[i];
    ushort4 o;
    o.x = f2bf(v.x); o.y = f2bf(v.y); o.z = f2bf(v.z); o.w = f2bf(v.w);
    *(ushort4*)(Wb + (size_t)i * 4) = o;
    return;
  }
  int row = bx - 1088;
  const float4* p = (const float4*)(adj + (size_t)row * NN);
  float s = 0.f;
#pragma unroll
  for (int c = 0; c < 2; ++c) {
    float4 v = p[t + 256 * c];
    s += v.x + v.y + v.z + v.w;
  }
#pragma unroll
  for (int off = 32; off > 0; off >>= 1) s += __shfl_down(s, off, 64);
  int lane = t & 63, w = t >> 6;
  if (lane == 0) red[w] = s;
  __syncthreads();
  if (t == 0) {
    float tt = red[0] + red[1] + red[2] + red[3] + 1.0f;
    d[row] = 1.0f / sqrtf(tt);
  }
}

// ---- Fused: H = d_i*((adj·diag(d))@Y + d_i*Y_i) ; out = relu(H@W^T + b) ----
// BM=64, BN=256, BK=32, 512 thr (8 waves 2x4), grid 256 = 1 block/CU.
// ONE s_barrier per pair (2 K-steps) => wave skew < 1 pair by construction.
// B: glds, 6 bufs mod-3-pairs (read G%3, write (G+1)%3, lag uses (G+2)%3).
// A: fp32 adj * d_j -> bf16 regs->ds_write, 3 granules mod-3 (write (G+2)%3).
#define BBASE 24576

#define MFMA8X(A0, A1, B0, B1, B2, B3)                                         \
    __builtin_amdgcn_s_setprio(1);                                             \
    acc[0][0] = __builtin_amdgcn_mfma_f32_16x16x32_bf16(A0, B0, acc[0][0], 0, 0, 0); \
    acc[0][1] = __builtin_amdgcn_mfma_f32_16x16x32_bf16(A0, B1, acc[0][1], 0, 0, 0); \
    acc[0][2] = __builtin_amdgcn_mfma_f32_16x16x32_bf16(A0, B2, acc[0][2], 0, 0, 0); \
    acc[0][3] = __builtin_amdgcn_mfma_f32_16x16x32_bf16(A0, B3, acc[0][3], 0, 0, 0); \
    acc[1][0] = __builtin_amdgcn_mfma_f32_16x16x32_bf16(A1, B0, acc[1][0], 0, 0, 0); \
    acc[1][1] = __builtin_amdgcn_mfma_f32_16x16x32_bf16(A1, B1, acc[1][1], 0, 0, 0); \
    acc[1][2] = __builtin_amdgcn_mfma_f32_16x16x32_bf16(A1, B2, acc[1][2], 0, 0, 0); \
    acc[1][3] = __builtin_amdgcn_mfma_f32_16x16x32_bf16(A1, B3, acc[1][3], 0, 0, 0); \
    __builtin_amdgcn_s_setprio(0);

#define AWRITED(S, G_)                                                         \
    {                                                                          \
      float4 c0 = aN0[S], c1 = aN1[S], e0 = dN0[S], e1 = dN1[S];               \
      u16x8 pk;                                                                \
      pk[0] = f2bf(c0.x * e0.x); pk[1] = f2bf(c0.y * e0.y);                    \
      pk[2] = f2bf(c0.z * e0.z); pk[3] = f2bf(c0.w * e0.w);                    \
      pk[4] = f2bf(c1.x * e1.x); pk[5] = f2bf(c1.y * e1.y);                    \
      pk[6] = f2bf(c1.z * e1.z); pk[7] = f2bf(c1.w * e1.w);                    \
      *(u16x8*)(smem + (G_) * 8192 + a_ldst) = pk;                             \
    }

// Pair G: RG=G%3 granule read; GW=(G+2)%3 granule+set written; SL=(G+1)%3 set
// loaded (pair G+4 data); BRB=(G%3)*2 bufs read; BWB=((G+1)%3)*2 bufs written.
#define PAIRX(G, RG, GW, SL, BRB, BWB, VMC, IA, WA, IB)                        \
  {                                                                            \
    if (IB) {                                                                  \
      gload_lds16(b_src0 + (size_t)(2 * (G) + 2) * 32,                         \
                  smem + BBASE + (BWB) * 16384 + bw0);                         \
      gload_lds16(b_src1 + (size_t)(2 * (G) + 2) * 32,                         \
                  smem + BBASE + (BWB) * 16384 + bw1);                         \
      gload_lds16(b_src0 + (size_t)(2 * (G) + 3) * 32,                         \
                  smem + BBASE + ((BWB) + 1) * 16384 + bw0);                   \
      gload_lds16(b_src1 + (size_t)(2 * (G) + 3) * 32,                         \
                  smem + BBASE + ((BWB) + 1) * 16384 + bw1);                   \
    }                                                                          \
    if (IA) {                                                                  \
      aN0[SL] = *(const float4*)(a_gsrc + (size_t)((G) + 4) * 64);             \
      aN1[SL] = *(const float4*)(a_gsrc + (size_t)((G) + 4) * 64 + 4);         \
      dN0[SL] = *(const float4*)(d_gsrc + (size_t)((G) + 4) * 64);             \
      dN1[SL] = *(const float4*)(d_gsrc + (size_t)((G) + 4) * 64 + 4);         \
    }                                                                          \
    __builtin_amdgcn_sched_barrier(0);                                         \
    asm volatile("s_waitcnt vmcnt(" VMC ")" ::: "memory");                     \
    __builtin_amdgcn_sched_barrier(0);                                         \
    __builtin_amdgcn_s_barrier();                                              \
    __builtin_amdgcn_sched_barrier(0);                                         \
    const char* Ab = smem + (RG) * 8192;                                       \
    const char* Be = smem + BBASE + (BRB) * 16384;                             \
    const char* Bo = smem + BBASE + ((BRB) + 1) * 16384;                       \
    bf16x8 a00 = *(const bf16x8*)(Ab + aoff0);                                 \
    bf16x8 a01 = *(const bf16x8*)(Ab + aoff0 + 1024);                          \
    bf16x8 be0 = *(const bf16x8*)(Be + boff0);                                 \
    bf16x8 be1 = *(const bf16x8*)(Be + boff0 + 1024);                          \
    bf16x8 be2 = *(const bf16x8*)(Be + boff0 + 2048);                          \
    bf16x8 be3 = *(const bf16x8*)(Be + boff0 + 3072);                          \
    __builtin_amdgcn_sched_barrier(0);                                         \
    bf16x8 a10 = *(const bf16x8*)(Ab + 4096 + aoff0);                          \
    bf16x8 a11 = *(const bf16x8*)(Ab + 4096 + aoff0 + 1024);                   \
    bf16x8 bo0 = *(const bf16x8*)(Bo + boff0);                                 \
    bf16x8 bo1 = *(const bf16x8*)(Bo + boff0 + 1024);                          \
    bf16x8 bo2 = *(const bf16x8*)(Bo + boff0 + 2048);                          \
    bf16x8 bo3 = *(const bf16x8*)(Bo + boff0 + 3072);                          \
    asm volatile("s_waitcnt lgkmcnt(6)" ::: "memory");                         \
    __builtin_amdgcn_sched_barrier(0);                                         \
    MFMA8X(a00, a01, be0, be1, be2, be3)                                       \
    __builtin_amdgcn_sched_barrier(0);                                         \
    asm volatile("s_waitcnt lgkmcnt(0)" ::: "memory");                         \
    __builtin_amdgcn_sched_barrier(0);                                         \
    MFMA8X(a10, a11, bo0, bo1, bo2, bo3)                                       \
    __builtin_amdgcn_sched_barrier(0);                                         \
    if (WA) { AWRITED(GW, GW) }                                                \
    __builtin_amdgcn_sched_barrier(0);                                         \
  }

__global__ __launch_bounds__(512, 2) void k_fused(
    const float* __restrict__ adj, const u16* __restrict__ YpT,
    const float* __restrict__ dsc, const u16* __restrict__ Wb,
    const float* __restrict__ bias, float* __restrict__ out) {
  int flat = blockIdx.x;
  int b = flat & 7, mt = flat >> 3;  // batch->XCD affinity
  int i0 = mt * 64;

  __shared__ __align__(16) char smem[122880];  // A 3x8K | B 6x16K ; Hs aliases
  u16* Hs = (u16*)smem;                        // 64 x 264 u16 = 33.8 KB

  int t = threadIdx.x;
  int lane = t & 63, w = t >> 6;
  int l15 = lane & 15, l4 = lane >> 4;
  int wr = w >> 2, wc = w & 3;

  const float* adjf = adj + ((size_t)b * NN + i0) * NN;
  const u16* YpTb = YpT + (size_t)b * NF * NN;

  // A staging: thread t -> row rA=t>>3, 8-float chunk kc=t&7 per pair
  int rA = t >> 3, kc = t & 7;
  const float* a_gsrc = adjf + (size_t)rA * NN + kc * 8;
  const float* d_gsrc = dsc + b * NN + kc * 8;
  int a_ldst = (kc >> 2) * 4096 + rA * 64 + (((kc & 3) ^ ((rA >> 1) & 3)) << 4);

  // B staging (glds, source-swizzled): slots t and t+512 of [256][32]
  int n0s = t >> 2, c0s = t & 3;
  const u16* b_src0 = YpTb + (size_t)n0s * NN + ((c0s ^ ((n0s >> 1) & 3)) << 3);
  int s1 = 512 + t;
  int n1s = s1 >> 2, c1s = s1 & 3;
  const u16* b_src1 = YpTb + (size_t)n1s * NN + ((c1s ^ ((n1s >> 1) & 3)) << 3);
  int bw0 = w << 10;
  int bw1 = 8192 + (w << 10);

  // frag read byte offsets
  int swz = (l4 ^ ((l15 >> 1) & 3)) << 4;
  int aoff0 = wr * 2048 + l15 * 64 + swz;
  int boff0 = (wc * 64 + l15) * 64 + swz;

  f32x4 acc[2][4] = {};
  float4 aN0[3], aN1[3], dN0[3], dN1[3];

  // ---- prologue ----
  {
    float4 p0a = *(const float4*)(a_gsrc);           // A pair 0
    float4 p0b = *(const float4*)(a_gsrc + 4);
    float4 p1a = *(const float4*)(a_gsrc + 64);      // A pair 1
    float4 p1b = *(const float4*)(a_gsrc + 68);
    float4 q0a = *(const float4*)(d_gsrc);           // d pair 0
    float4 q0b = *(const float4*)(d_gsrc + 4);
    float4 q1a = *(const float4*)(d_gsrc + 64);      // d pair 1
    float4 q1b = *(const float4*)(d_gsrc + 68);
    __builtin_amdgcn_sched_barrier(0);
    gload_lds16(b_src0, smem + BBASE + bw0);               // B step0 -> buf0
    gload_lds16(b_src1, smem + BBASE + bw1);
    gload_lds16(b_src0 + 32, smem + BBASE + 16384 + bw0);  // B step1 -> buf1
    gload_lds16(b_src1 + 32, smem + BBASE + 16384 + bw1);
    __builtin_amdgcn_sched_barrier(0);
    aN0[2] = *(const float4*)(a_gsrc + 128);         // pair 2 -> set 2
    aN1[2] = *(const float4*)(a_gsrc + 132);
    dN0[2] = *(const float4*)(d_gsrc + 128);
    dN1[2] = *(const float4*)(d_gsrc + 132);
    aN0[0] = *(const float4*)(a_gsrc + 192);         // pair 3 -> set 0
    aN1[0] = *(const float4*)(a_gsrc + 196);
    dN0[0] = *(const float4*)(d_gsrc + 192);
    dN1[0] = *(const float4*)(d_gsrc + 196);
    __builtin_amdgcn_sched_barrier(0);
    u16x8 pk;
    pk[0] = f2bf(p0a.x * q0a.x); pk[1] = f2bf(p0a.y * q0a.y);
    pk[2] = f2bf(p0a.z * q0a.z); pk[3] = f2bf(p0a.w * q0a.w);
    pk[4] = f2bf(p0b.x * q0b.x); pk[5] = f2bf(p0b.y * q0b.y);
    pk[6] = f2bf(p0b.z * q0b.z); pk[7] = f2bf(p0b.w * q0b.w);
    *(u16x8*)(smem + a_ldst) = pk;                   // granule 0
    pk[0] = f2bf(p1a.x * q1a.x); pk[1] = f2bf(p1a.y * q1a.y);
    pk[2] = f2bf(p1a.z * q1a.z); pk[3] = f2bf(p1a.w * q1a.w);
    pk[4] = f2bf(p1b.x * q1b.x); pk[5] = f2bf(p1b.y * q1b.y);
    pk[6] = f2bf(p1b.z * q1b.z); pk[7] = f2bf(p1b.w * q1b.w);
    *(u16x8*)(smem + 8192 + a_ldst) = pk;            // granule 1
    asm volatile("s_waitcnt lgkmcnt(0)" ::: "memory");
    __builtin_amdgcn_sched_barrier(0);
  }

  // ---- pairs 0..2 peeled (P0 has prologue-adjusted vmcnt) ----
  PAIRX(0, 0, 2, 1, 0, 2, "16", 1, 1, 1)
  PAIRX(1, 1, 0, 2, 2, 4, "12", 1, 1, 1)
  PAIRX(2, 2, 1, 0, 4, 0, "12", 1, 1, 1)
  // ---- main loop: pairs 3..26 (8 x 3) ----
  for (int gb = 1; gb < 9; ++gb) {
    int g = gb * 3;
    PAIRX(g + 0, 0, 2, 1, 0, 2, "12", 1, 1, 1)
    PAIRX(g + 1, 1, 0, 2, 2, 4, "12", 1, 1, 1)
    PAIRX(g + 2, 2, 1, 0, 4, 0, "12", 1, 1, 1)
  }
  // ---- tail: pairs 27..31 ----
  PAIRX(27, 0, 2, 1, 0, 2, "12", 1, 1, 1)
  PAIRX(28, 1, 0, 2, 2, 4, "8", 0, 1, 1)
  PAIRX(29, 2, 1, 0, 4, 0, "4", 0, 1, 1)
  PAIRX(30, 0, 2, 1, 0, 2, "4", 0, 0, 1)
  PAIRX(31, 1, 0, 2, 2, 4, "0", 0, 0, 0)

  __syncthreads();  // drain all before Hs aliases staging buffers

  // ---- epilogue 1: H -> LDS bf16 [64][264]; +I term d_i^2 * Y (L2) ----
  const float* db = dsc + b * NN;
#pragma unroll
  for (int mi = 0; mi < 2; ++mi) {
#pragma unroll
    for (int ni = 0; ni < 4; ++ni) {
      int f = wc * 64 + ni * 16 + l15;
      ushort4 xv = *(const ushort4*)(YpTb + (size_t)f * NN + i0 +
                                     wr * 32 + mi * 16 + l4 * 4);
#pragma unroll
      for (int qq = 0; qq < 4; ++qq) {
        int il = wr * 32 + mi * 16 + l4 * 4 + qq;
        float dv = db[i0 + il];
        float xpv = bf2f(((const u16*)&xv)[qq]);
        float hv = dv * (acc[mi][ni][qq] + dv * xpv);
        Hs[il * 264 + f] = f2bf(hv);
      }
    }
  }
  __syncthreads();

  // ---- epilogue 2: out = relu(H @ W^T + bias), W frags from L2 ----
  f32x4 acc2[2][4] = {};
#pragma unroll
  for (int kk = 0; kk < 256; kk += 32) {
    bf16x8 a2[2], b2[4];
#pragma unroll
    for (int mi = 0; mi < 2; ++mi) {
      int r = wr * 32 + mi * 16 + l15;
      a2[mi] = *(const bf16x8*)&Hs[r * 264 + kk + l4 * 8];
    }
#pragma unroll
    for (int ni = 0; ni < 4; ++ni) {
      int o = wc * 64 + ni * 16 + l15;
      b2[ni] = *(const bf16x8*)&Wb[(size_t)o * 256 + kk + l4 * 8];
    }
#pragma unroll
    for (int mi = 0; mi < 2; ++mi)
#pragma unroll
      for (int ni = 0; ni < 4; ++ni)
        acc2[mi][ni] = __builtin_amdgcn_mfma_f32_16x16x32_bf16(a2[mi], b2[ni],
                                                               acc2[mi][ni], 0, 0, 0);
  }

  float* outb = out + ((size_t)b * NN + i0) * NF;
#pragma unroll
  for (int mi = 0; mi < 2; ++mi) {
#pragma unroll
    for (int qq = 0; qq < 4; ++qq) {
      int il = wr * 32 + mi * 16 + l4 * 4 + qq;
#pragma unroll
      for (int ni = 0; ni < 4; ++ni) {
        int o = wc * 64 + ni * 16 + l15;
        float v = acc2[mi][ni][qq] + bias[o];
        outb[(size_t)il * NF + o] = fmaxf(v, 0.f);
      }
    }
  }
}

extern "C" void kernel_launch(void* const* d_in, const int* in_sizes, int n_in,
                              void* d_out, int out_size, void* d_ws, size_t ws_size,
                              hipStream_t stream) {
  const float* X    = (const float*)d_in[0];
  const float* adj  = (const float*)d_in[1];
  const float* W    = (const float*)d_in[2];
  const float* bias = (const float*)d_in[3];
  float* out = (float*)d_out;

  char* ws = (char*)d_ws;
  float* dsc = (float*)(ws);                 // 64 KB
  u16*   Wb  = (u16*)(ws + 65536);           // 128 KB
  u16*   YpT = (u16*)(ws + 262144);          // 8 MB

  k_pre<<<dim3(17472), dim3(256), 0, stream>>>(adj, dsc, X, YpT, W, Wb);
  k_fused<<<dim3(256), dim3(512), 0, stream>>>(adj, YpT, dsc, Wb, bias, out);
}

// Round 13
// 72.229 us; speedup vs baseline: 1.4567x; 1.0810x over previous
//
#include <hip/hip_runtime.h>
#include <stdint.h>

typedef __attribute__((ext_vector_type(8))) short bf16x8;
typedef __attribute__((ext_vector_type(8))) unsigned short u16x8;
typedef __attribute__((ext_vector_type(4))) float f32x4;
typedef unsigned short u16;

constexpr int NN = 2048, NF = 256;

__device__ inline u16 f2bf(float f) {
  uint32_t u = __builtin_bit_cast(uint32_t, f);
  uint32_t r = (u + 0x7FFFu + ((u >> 16) & 1u)) >> 16;
  return (u16)r;
}
__device__ inline float bf2f(u16 h) {
  uint32_t u = ((uint32_t)h) << 16;
  return __builtin_bit_cast(float, u);
}

__device__ inline void gload_lds16(const void* g, void* l) {
  __builtin_amdgcn_global_load_lds(
      (const __attribute__((address_space(1))) uint32_t*)g,
      (__attribute__((address_space(3))) uint32_t*)l,
      16, 0, 0);
}

// ---- K1: d[row]=rsqrt(1+sum adj[row,:]); tail blocks: Wconv ----------------
__global__ __launch_bounds__(256) void k_rowsum(const float* __restrict__ adj,
                                                float* __restrict__ d,
                                                const float* __restrict__ W,
                                                u16* __restrict__ Wb) {
  if (blockIdx.x >= 16384) {
    int i = (blockIdx.x - 16384) * 256 + threadIdx.x;
    float4 v = ((const float4*)W)[i];
    ushort4 o;
    o.x = f2bf(v.x); o.y = f2bf(v.y); o.z = f2bf(v.z); o.w = f2bf(v.w);
    *(ushort4*)(Wb + (size_t)i * 4) = o;
    return;
  }
  int row = blockIdx.x;
  const float4* p = (const float4*)(adj + (size_t)row * NN);
  float s = 0.f;
#pragma unroll
  for (int c = 0; c < 2; ++c) {
    float4 v = p[threadIdx.x + 256 * c];
    s += v.x + v.y + v.z + v.w;
  }
#pragma unroll
  for (int off = 32; off > 0; off >>= 1) s += __shfl_down(s, off, 64);
  __shared__ float red[4];
  int lane = threadIdx.x & 63, w = threadIdx.x >> 6;
  if (lane == 0) red[w] = s;
  __syncthreads();
  if (threadIdx.x == 0) {
    float t = red[0] + red[1] + red[2] + red[3] + 1.0f;
    d[row] = 1.0f / sqrtf(t);
  }
}

// ---- K2: XpT[b,f,j] = bf16(d_j * X[b,j,f])  (plain transpose) --------------
__global__ __launch_bounds__(256) void k_xprep(const float* __restrict__ X,
                                               const float* __restrict__ d,
                                               u16* __restrict__ XpT) {
  int jt = blockIdx.x, ft = blockIdx.y, b = blockIdx.z;
  int j0 = jt * 64, f0 = ft * 64;
  __shared__ u16 T[64][66];
  int t = threadIdx.x;
#pragma unroll
  for (int s = 0; s < 4; ++s) {
    int q = s * 256 + t;
    int r = q >> 4, c4 = q & 15;
    int j = j0 + r;
    float dv = d[b * NN + j];
    float4 v = *(const float4*)(X + ((size_t)(b * NN + j)) * NF + f0 + c4 * 4);
    T[r][c4 * 4 + 0] = f2bf(v.x * dv);
    T[r][c4 * 4 + 1] = f2bf(v.y * dv);
    T[r][c4 * 4 + 2] = f2bf(v.z * dv);
    T[r][c4 * 4 + 3] = f2bf(v.w * dv);
  }
  __syncthreads();
#pragma unroll
  for (int s = 0; s < 4; ++s) {
    int q = s * 256 + t;
    int fr = q >> 4, c4 = q & 15;
    ushort4 o;
    o.x = T[c4 * 4 + 0][fr]; o.y = T[c4 * 4 + 1][fr];
    o.z = T[c4 * 4 + 2][fr]; o.w = T[c4 * 4 + 3][fr];
    *(ushort4*)(XpT + ((size_t)(b * NF + f0 + fr)) * NN + j0 + c4 * 4) = o;
  }
}

// ---- Fused: H = d_i*(adj@Xp + Xp_i) ; out = relu(H@W^T + bias) -------------
// BM=64, BN=256, BK=64 per barrier (32 steps), 512 thr (8 waves 2x4), 1 blk/CU.
// Per-step barrier => skew window = 1 step => 3 bufs for A and B (mod 3):
// read slot S%3, write slot (S+2)%3. B: glds depth-2; A: fp32 regs->cvt->ds.
#define BBASE 24576

#define MFMA8X(A0, A1, B0, B1, B2, B3)                                         \
    __builtin_amdgcn_s_setprio(1);                                             \
    acc[0][0] = __builtin_amdgcn_mfma_f32_16x16x32_bf16(A0, B0, acc[0][0], 0, 0, 0); \
    acc[0][1] = __builtin_amdgcn_mfma_f32_16x16x32_bf16(A0, B1, acc[0][1], 0, 0, 0); \
    acc[0][2] = __builtin_amdgcn_mfma_f32_16x16x32_bf16(A0, B2, acc[0][2], 0, 0, 0); \
    acc[0][3] = __builtin_amdgcn_mfma_f32_16x16x32_bf16(A0, B3, acc[0][3], 0, 0, 0); \
    acc[1][0] = __builtin_amdgcn_mfma_f32_16x16x32_bf16(A1, B0, acc[1][0], 0, 0, 0); \
    acc[1][1] = __builtin_amdgcn_mfma_f32_16x16x32_bf16(A1, B1, acc[1][1], 0, 0, 0); \
    acc[1][2] = __builtin_amdgcn_mfma_f32_16x16x32_bf16(A1, B2, acc[1][2], 0, 0, 0); \
    acc[1][3] = __builtin_amdgcn_mfma_f32_16x16x32_bf16(A1, B3, acc[1][3], 0, 0, 0); \
    __builtin_amdgcn_s_setprio(0);

// Step KS (64 k-cols). R3 = KS%3 (read slot), W3 = (KS+2)%3 (write slot).
#define STEP(KS, R3, W3, VMC, IA, WA, IB)                                      \
  {                                                                            \
    if (IB) {                                                                  \
      gload_lds16(b_src0 + (size_t)((KS) + 2) * 64,                            \
                  smem + BBASE + (W3) * 32768 + bw0);                          \
      gload_lds16(b_src1 + (size_t)((KS) + 2) * 64,                            \
                  smem + BBASE + (W3) * 32768 + bw1);                          \
      gload_lds16(b_src0 + (size_t)((KS) + 2) * 64 + 32,                       \
                  smem + BBASE + (W3) * 32768 + 16384 + bw0);                  \
      gload_lds16(b_src1 + (size_t)((KS) + 2) * 64 + 32,                       \
                  smem + BBASE + (W3) * 32768 + 16384 + bw1);                  \
    }                                                                          \
    if (IA) {                                                                  \
      aN0[R3] = *(const float4*)(a_gsrc + (size_t)((KS) + 3) * 64);            \
      aN1[R3] = *(const float4*)(a_gsrc + (size_t)((KS) + 3) * 64 + 4);        \
    }                                                                          \
    __builtin_amdgcn_sched_barrier(0);                                         \
    asm volatile("s_waitcnt vmcnt(" VMC ") lgkmcnt(0)" ::: "memory");          \
    __builtin_amdgcn_sched_barrier(0);                                         \
    __builtin_amdgcn_s_barrier();                                              \
    __builtin_amdgcn_sched_barrier(0);                                         \
    const char* Ab = smem + (R3) * 8192;                                       \
    const char* Be = smem + BBASE + (R3) * 32768;                              \
    const char* Bo = Be + 16384;                                               \
    bf16x8 a00 = *(const bf16x8*)(Ab + aoff0);                                 \
    bf16x8 a01 = *(const bf16x8*)(Ab + aoff0 + 1024);                          \
    bf16x8 be0 = *(const bf16x8*)(Be + boff0);                                 \
    bf16x8 be1 = *(const bf16x8*)(Be + boff0 + 1024);                          \
    bf16x8 be2 = *(const bf16x8*)(Be + boff0 + 2048);                          \
    bf16x8 be3 = *(const bf16x8*)(Be + boff0 + 3072);                          \
    __builtin_amdgcn_sched_barrier(0);                                         \
    bf16x8 a10 = *(const bf16x8*)(Ab + 4096 + aoff0);                          \
    bf16x8 a11 = *(const bf16x8*)(Ab + 4096 + aoff0 + 1024);                   \
    bf16x8 bo0 = *(const bf16x8*)(Bo + boff0);                                 \
    bf16x8 bo1 = *(const bf16x8*)(Bo + boff0 + 1024);                          \
    bf16x8 bo2 = *(const bf16x8*)(Bo + boff0 + 2048);                          \
    bf16x8 bo3 = *(const bf16x8*)(Bo + boff0 + 3072);                          \
    asm volatile("s_waitcnt lgkmcnt(6)" ::: "memory");                         \
    __builtin_amdgcn_sched_barrier(0);                                         \
    MFMA8X(a00, a01, be0, be1, be2, be3)                                       \
    __builtin_amdgcn_sched_barrier(0);                                         \
    asm volatile("s_waitcnt lgkmcnt(0)" ::: "memory");                         \
    __builtin_amdgcn_sched_barrier(0);                                         \
    MFMA8X(a10, a11, bo0, bo1, bo2, bo3)                                       \
    __builtin_amdgcn_sched_barrier(0);                                         \
    if (WA) {                                                                  \
      float4 c0 = aN0[W3], c1 = aN1[W3];                                       \
      u16x8 pk;                                                                \
      pk[0] = f2bf(c0.x); pk[1] = f2bf(c0.y); pk[2] = f2bf(c0.z);              \
      pk[3] = f2bf(c0.w); pk[4] = f2bf(c1.x); pk[5] = f2bf(c1.y);              \
      pk[6] = f2bf(c1.z); pk[7] = f2bf(c1.w);                                  \
      *(u16x8*)(smem + (W3) * 8192 + a_ldst) = pk;                             \
    }                                                                          \
    __builtin_amdgcn_sched_barrier(0);                                         \
  }

__global__ __launch_bounds__(512, 2) void k_fused(
    const float* __restrict__ adj, const u16* __restrict__ XpT,
    const float* __restrict__ dsc, const u16* __restrict__ Wb,
    const float* __restrict__ bias, float* __restrict__ out) {
  int flat = blockIdx.x;
  int b = flat & 7, mt = flat >> 3;  // batch->XCD affinity
  int i0 = mt * 64;

  __shared__ __align__(16) char smem[122880];  // A 3x8K | B 3x32K ; Hs aliases
  u16* Hs = (u16*)smem;

  int t = threadIdx.x;
  int lane = t & 63, w = t >> 6;
  int l15 = lane & 15, l4 = lane >> 4;
  int wr = w >> 2, wc = w & 3;

  const float* adjf = adj + ((size_t)b * NN + i0) * NN;
  const u16* XpTb = XpT + (size_t)b * NF * NN;

  // A staging: thread t -> row rA=t>>3, 8-float chunk kc=t&7 within 64-k step
  int rA = t >> 3, kc = t & 7;
  const float* a_gsrc = adjf + (size_t)rA * NN + kc * 8;
  int a_ldst = (kc >> 2) * 4096 + rA * 64 + (((kc & 3) ^ ((rA >> 1) & 3)) << 4);

  // B staging (glds, source-swizzled): slots t and t+512 of [256][32] per half
  int n0s = t >> 2, c0s = t & 3;
  const u16* b_src0 = XpTb + (size_t)n0s * NN + ((c0s ^ ((n0s >> 1) & 3)) << 3);
  int s1 = 512 + t;
  int n1s = s1 >> 2, c1s = s1 & 3;
  const u16* b_src1 = XpTb + (size_t)n1s * NN + ((c1s ^ ((n1s >> 1) & 3)) << 3);
  int bw0 = w << 10;
  int bw1 = 8192 + (w << 10);

  // frag read byte offsets
  int swz = (l4 ^ ((l15 >> 1) & 3)) << 4;
  int aoff0 = wr * 2048 + l15 * 64 + swz;
  int boff0 = (wc * 64 + l15) * 64 + swz;

  f32x4 acc[2][4] = {};
  float4 aN0[3], aN1[3];

  // ---- prologue: A steps 0,1 -> granules 0,1; B steps 0,1 -> bufs 0,1;
  //      A step 2 -> reg set 2 ----
  {
    float4 p0a = *(const float4*)(a_gsrc);
    float4 p0b = *(const float4*)(a_gsrc + 4);
    float4 p1a = *(const float4*)(a_gsrc + 64);
    float4 p1b = *(const float4*)(a_gsrc + 68);
    __builtin_amdgcn_sched_barrier(0);
    gload_lds16(b_src0, smem + BBASE + bw0);
    gload_lds16(b_src1, smem + BBASE + bw1);
    gload_lds16(b_src0 + 32, smem + BBASE + 16384 + bw0);
    gload_lds16(b_src1 + 32, smem + BBASE + 16384 + bw1);
    gload_lds16(b_src0 + 64, smem + BBASE + 32768 + bw0);
    gload_lds16(b_src1 + 64, smem + BBASE + 32768 + bw1);
    gload_lds16(b_src0 + 96, smem + BBASE + 32768 + 16384 + bw0);
    gload_lds16(b_src1 + 96, smem + BBASE + 32768 + 16384 + bw1);
    __builtin_amdgcn_sched_barrier(0);
    aN0[2] = *(const float4*)(a_gsrc + 128);  // step 2 -> set 2
    aN1[2] = *(const float4*)(a_gsrc + 132);
    __builtin_amdgcn_sched_barrier(0);
    u16x8 pk;
    pk[0] = f2bf(p0a.x); pk[1] = f2bf(p0a.y); pk[2] = f2bf(p0a.z);
    pk[3] = f2bf(p0a.w); pk[4] = f2bf(p0b.x); pk[5] = f2bf(p0b.y);
    pk[6] = f2bf(p0b.z); pk[7] = f2bf(p0b.w);
    *(u16x8*)(smem + a_ldst) = pk;            // granule 0
    pk[0] = f2bf(p1a.x); pk[1] = f2bf(p1a.y); pk[2] = f2bf(p1a.z);
    pk[3] = f2bf(p1a.w); pk[4] = f2bf(p1b.x); pk[5] = f2bf(p1b.y);
    pk[6] = f2bf(p1b.z); pk[7] = f2bf(p1b.w);
    *(u16x8*)(smem + 8192 + a_ldst) = pk;     // granule 1
    __builtin_amdgcn_sched_barrier(0);
  }

  // ---- steps 0,1 peeled (prologue-adjusted vmcnt) ----
  STEP(0, 0, 2, "10", 1, 1, 1)
  STEP(1, 1, 0, "12", 1, 1, 1)
  // ---- main loop: steps 2..25 (8 x 3, period-3 literals) ----
  for (int sb = 2; sb <= 23; sb += 3) {
    STEP(sb + 0, 2, 1, "12", 1, 1, 1)
    STEP(sb + 1, 0, 2, "12", 1, 1, 1)
    STEP(sb + 2, 1, 0, "12", 1, 1, 1)
  }
  // ---- tail: steps 26..31 ----
  STEP(26, 2, 1, "12", 1, 1, 1)
  STEP(27, 0, 2, "12", 1, 1, 1)
  STEP(28, 1, 0, "12", 1, 1, 1)
  STEP(29, 2, 1, "12", 0, 1, 1)
  STEP(30, 0, 2, "4", 0, 0, 0)
  STEP(31, 1, 0, "0", 0, 0, 0)

  __syncthreads();  // drain all before Hs aliases staging buffers

  // ---- epilogue 1: H -> LDS bf16 [64][264]; +I term from XpT (L2) ----
  const float* db = dsc + b * NN;
#pragma unroll
  for (int mi = 0; mi < 2; ++mi) {
#pragma unroll
    for (int ni = 0; ni < 4; ++ni) {
      int f = wc * 64 + ni * 16 + l15;
      ushort4 xv = *(const ushort4*)(XpTb + (size_t)f * NN + i0 +
                                     wr * 32 + mi * 16 + l4 * 4);
#pragma unroll
      for (int qq = 0; qq < 4; ++qq) {
        int il = wr * 32 + mi * 16 + l4 * 4 + qq;
        float dv = db[i0 + il];
        float xpv = bf2f(((const u16*)&xv)[qq]);
        float hv = dv * (acc[mi][ni][qq] + xpv);
        Hs[il * 264 + f] = f2bf(hv);
      }
    }
  }
  __syncthreads();

  // ---- epilogue 2: out = relu(H @ W^T + bias), W frags from L2 ----
  f32x4 acc2[2][4] = {};
#pragma unroll
  for (int kk = 0; kk < 256; kk += 32) {
    bf16x8 a2[2], b2[4];
#pragma unroll
    for (int mi = 0; mi < 2; ++mi) {
      int r = wr * 32 + mi * 16 + l15;
      a2[mi] = *(const bf16x8*)&Hs[r * 264 + kk + l4 * 8];
    }
#pragma unroll
    for (int ni = 0; ni < 4; ++ni) {
      int o = wc * 64 + ni * 16 + l15;
      b2[ni] = *(const bf16x8*)&Wb[(size_t)o * 256 + kk + l4 * 8];
    }
#pragma unroll
    for (int mi = 0; mi < 2; ++mi)
#pragma unroll
      for (int ni = 0; ni < 4; ++ni)
        acc2[mi][ni] = __builtin_amdgcn_mfma_f32_16x16x32_bf16(a2[mi], b2[ni],
                                                               acc2[mi][ni], 0, 0, 0);
  }

  float* outb = out + ((size_t)b * NN + i0) * NF;
#pragma unroll
  for (int mi = 0; mi < 2; ++mi) {
#pragma unroll
    for (int qq = 0; qq < 4; ++qq) {
      int il = wr * 32 + mi * 16 + l4 * 4 + qq;
#pragma unroll
      for (int ni = 0; ni < 4; ++ni) {
        int o = wc * 64 + ni * 16 + l15;
        float v = acc2[mi][ni][qq] + bias[o];
        outb[(size_t)il * NF + o] = fmaxf(v, 0.f);
      }
    }
  }
}

extern "C" void kernel_launch(void* const* d_in, const int* in_sizes, int n_in,
                              void* d_out, int out_size, void* d_ws, size_t ws_size,
                              hipStream_t stream) {
  const float* X    = (const float*)d_in[0];
  const float* adj  = (const float*)d_in[1];
  const float* W    = (const float*)d_in[2];
  const float* bias = (const float*)d_in[3];
  float* out = (float*)d_out;

  char* ws = (char*)d_ws;
  float* dsc = (float*)(ws);                 // 64 KB
  u16*   Wb  = (u16*)(ws + 65536);           // 128 KB
  u16*   XpT = (u16*)(ws + 262144);          // 8 MB

  k_rowsum<<<dim3(16448), dim3(256), 0, stream>>>(adj, dsc, W, Wb);
  k_xprep<<<dim3(32, 4, 8), dim3(256), 0, stream>>>(X, dsc, XpT);
  k_fused<<<dim3(256), dim3(512), 0, stream>>>(adj, XpT, dsc, Wb, bias, out);
}